// Round 22
// baseline (386.669 us; speedup 1.0000x reference)
//
#include <hip/hip_runtime.h>
#include <math.h>

#define Nn 512
#define Mm 32000
#define Bb 64
#define Tt 256
#define NCONS 4     // consumer (recursion) blocks
#define NPROD 128   // producer (emission gather) blocks
#define NPRE  412   // pre blocks (rowsum grid-stride; first 32 also colsum)

typedef float v4f __attribute__((ext_vector_type(4)));
typedef float f4  __attribute__((ext_vector_type(4)));
typedef int   v4i __attribute__((ext_vector_type(4)));
typedef int   v8i __attribute__((ext_vector_type(8)));

// pack 4 f32 -> 4 OCP e4m3 bytes in an int
__device__ inline int pk4fp8(float a, float b, float c, float d) {
  int r = __builtin_amdgcn_cvt_pk_fp8_f32(a, b, 0, false);
  r = __builtin_amdgcn_cvt_pk_fp8_f32(c, d, r, true);
  return r;
}

// ---- ONE kernel, three roles; only consumers ever spin (no deadlock any order) ----
// progress[0..7]: Pem2 32-t chunks (to NPROD); [8]: rowsum blocks done (to NPRE);
// progress[9]: colsum blocks done (to 32).
__global__ __attribute__((amdgpu_flat_work_group_size(512, 512), amdgpu_waves_per_eu(2, 2)))
void k_all(
    const float* __restrict__ trans, const float* __restrict__ emis,
    const int* __restrict__ x, const float* __restrict__ prior,
    const int* __restrict__ Tlen, float* __restrict__ colsum,
    float* __restrict__ rowsum, float* __restrict__ Pem2,
    int* __restrict__ progress, float* __restrict__ out)
{
  __shared__ __align__(16) char ybuf[2][16 * Nn];   // consumer: fp8 Y dbuf (16 KB)
  __shared__ __align__(16) float ss[512];
  const int tid = threadIdx.x;
  const int bid = blockIdx.x;

  if (bid >= NCONS + NPROD) {
    // ================= pre: colsum stripe (q<32) + rowsum rows, then EXIT =================
    const int q = bid - (NCONS + NPROD);   // 0..411
    if (q < 32) {
      int j0 = q * 16;
      float a = 0.f;
      #pragma unroll 4
      for (int r = 0; r < 16; ++r) a += __expf(trans[(j0 + r) * Nn + tid]);
      atomicAdd(&colsum[tid], a);
      __syncthreads();
      if (tid == 0) {
        __builtin_amdgcn_fence(__ATOMIC_RELEASE, "agent");
        __hip_atomic_fetch_add(&progress[9], 1, __ATOMIC_RELAXED, __HIP_MEMORY_SCOPE_AGENT);
      }
    }
    for (int row = q; row < Nn; row += NPRE) {
      const f4* r4 = (const f4*)(emis + (size_t)row * Mm);
      float s = 0.f;
      for (int i = tid; i < Mm / 4; i += 512) {
        f4 v = r4[i];
        s += (__expf(v[0]) + __expf(v[1])) + (__expf(v[2]) + __expf(v[3]));
      }
      ss[tid] = s; __syncthreads();
      for (int off = 256; off; off >>= 1) { if (tid < off) ss[tid] += ss[tid + off]; __syncthreads(); }
      if (tid == 0) rowsum[row] = ss[0];
      __syncthreads();
    }
    if (tid == 0) {
      __builtin_amdgcn_fence(__ATOMIC_RELEASE, "agent");
      __hip_atomic_fetch_add(&progress[8], 1, __ATOMIC_RELAXED, __HIP_MEMORY_SCOPE_AGENT);
    }
    return;
  }

  if (bid >= NCONS) {
    // ================= producer: RAW gather (no deps), publish 32-t chunks =================
    const int p = bid - NCONS;             // j-quad p -> emis rows 4p..4p+3
    const int j0 = p * 4;
    const float* r0 = emis + (size_t)(j0 + 0) * Mm;
    const float* r1 = emis + (size_t)(j0 + 1) * Mm;
    const float* r2 = emis + (size_t)(j0 + 2) * Mm;
    const float* r3 = emis + (size_t)(j0 + 3) * Mm;
    f4* P4 = (f4*)Pem2;
    for (int c8 = 0; c8 < 8; ++c8) {
      #pragma unroll
      for (int r = 0; r < 4; ++r) {
        int idx = c8 * 2048 + r * 512 + tid;
        int t = idx >> 6, b = idx & 63;
        int mv = x[b * Tt + t];
        f4 o = { __expf(r0[mv]), __expf(r1[mv]), __expf(r2[mv]), __expf(r3[mv]) };
        P4[t * 8192 + (b >> 4) * 2048 + p * 16 + (b & 15)] = o;
      }
      __syncthreads();
      if (tid == 0) {
        __builtin_amdgcn_fence(__ATOMIC_RELEASE, "agent");
        __hip_atomic_fetch_add(&progress[c8], 1, __ATOMIC_RELAXED, __HIP_MEMORY_SCOPE_AGENT);
      }
    }
    return;
  }

  // ================= consumer: 8 waves, 64 A-rows each =================
  const int g = bid;
  const int w = tid >> 6, lane = tid & 63;
  const int c = lane & 15, kq = lane >> 4;
  const int jw = w * 64;                    // this wave's 64 A-rows
  const int swz = (c & 7) << 4;
  const int b = g * 16 + c;

  // ptot = sum exp(prior) — independent of pre-blocks, do while they scan
  float ptot;
  {
    float e = __expf(prior[tid]);
    ss[tid] = e; __syncthreads();
    for (int off = 256; off; off >>= 1) { if (tid < off) ss[tid] += ss[tid + off]; __syncthreads(); }
    ptot = ss[0];
    __syncthreads();
  }

  // wait for colsum + rowsum (all threads poll, then acquire)
  while (__hip_atomic_load(&progress[9], __ATOMIC_RELAXED, __HIP_MEMORY_SCOPE_AGENT) < 32 ||
         __hip_atomic_load(&progress[8], __ATOMIC_RELAXED, __HIP_MEMORY_SCOPE_AGENT) < NPRE)
    __builtin_amdgcn_s_sleep(2);
  __builtin_amdgcn_fence(__ATOMIC_ACQUIRE, "agent");

  // stage 1/colsum in LDS, then build af IN-REGISTER from trans (L2-hot):
  // A'[j][k] = 2^23 * exp(trans[j][k]) / (colsum[k] * rowsum[j])  as e4m3
  ss[tid] = 1.0f / colsum[tid];
  __syncthreads();
  v8i af[4][4];
  #pragma unroll
  for (int rt = 0; rt < 4; ++rt) {
    int jrow = jw + rt * 16 + c;
    float fr = 8388608.f / rowsum[jrow];
    const float* trow = trans + (size_t)jrow * Nn;
    #pragma unroll
    for (int kc = 0; kc < 4; ++kc) {
      int k0 = kc * 128 + kq * 32;
      int wd[8];
      #pragma unroll
      for (int u = 0; u < 8; ++u) {
        f4 tv = *(const f4*)(trow + k0 + u * 4);
        f4 cw = *(const f4*)(&ss[k0 + u * 4]);
        wd[u] = pk4fp8(fr * __expf(tv[0]) * cw[0], fr * __expf(tv[1]) * cw[1],
                       fr * __expf(tv[2]) * cw[2], fr * __expf(tv[3]) * cw[3]);
      }
      af[rt][kc] = (v8i){wd[0], wd[1], wd[2], wd[3], wd[4], wd[5], wd[6], wd[7]};
    }
  }

  // ones-A operand: e4m3 1.0 = 0x38 in all 32 bytes
  v8i onesv;
  #pragma unroll
  for (int u = 0; u < 8; ++u) onesv[u] = 0x38383838;

  // launder: block rematerialization/sinking into the loop
  #pragma unroll
  for (int rt = 0; rt < 4; ++rt)
    #pragma unroll
    for (int kc = 0; kc < 4; ++kc)
      asm volatile("" : "+v"(af[rt][kc]));
  asm volatile("" : "+v"(onesv));

  const int Tb = Tlen[b];
  int E = 23;                               // Y = 2^E * alpha
  int csafe = 0;

  #define ENSURE(NEED)                                                                      \
    while (csafe <= (NEED)) {                                                               \
      if (__hip_atomic_load(&progress[csafe], __ATOMIC_RELAXED,                             \
                            __HIP_MEMORY_SCOPE_AGENT) >= NPROD) {                           \
        ++csafe;                                                                            \
        __builtin_amdgcn_fence(__ATOMIC_ACQUIRE, "agent");                                  \
      } else __builtin_amdgcn_s_sleep(2);                                                   \
    }

  // LDS byte offsets. Writes use XOR (wf_rt = wf0 ^ rt*16); reads add kc*128.
  const int roA0 = (c * Nn + kq * 32) ^ swz;
  const int roB0 = roA0 ^ 16;
  const int wf0 = (c * Nn + jw + kq * 4) ^ swz;
  const int wf1 = wf0 ^ 16, wf2 = wf0 ^ 32, wf3 = wf0 ^ 48;
  char* const yb0 = &ybuf[0][0];

  const char* rdA_e = yb0 + roA0;          // odd-step read bases (buf0)
  const char* rdB_e = yb0 + roB0;
  const char* rdA_o = rdA_e + 8192;        // even-step read bases (buf1)
  const char* rdB_o = rdB_e + 8192;
  char* const wb_o = yb0 + 8192;           // odd-step write base (buf1)
  char* const wb_e = yb0;                  // even-step write base (buf0)

  ENSURE(0);                                // Pem2 chunk 0 ready

  // init: Y0 = 2^23 * pi[j]/rowsum[j] * Pem2raw[0][j][c']   (pi2 inlined)
  {
    int cc = tid & 15, grp = tid >> 4, jb = grp * 16, sz = (cc & 7) << 4;
    const f4* P0 = (const f4*)Pem2 + g * 2048 + (jb >> 2) * 16 + cc;
    float pf = 8388608.f / ptot;
    #pragma unroll
    for (int q = 0; q < 4; ++q) {
      int j = jb + q * 4;
      f4 pr = *(const f4*)(prior + j);
      f4 rw = *(const f4*)(rowsum + j);
      f4 v = P0[q * 16];
      f4 y;
      #pragma unroll
      for (int i = 0; i < 4; ++i) y[i] = v[i] * pf * __expf(pr[i]) / rw[i];
      *reinterpret_cast<int*>(yb0 + ((cc * Nn + j) ^ sz)) = pk4fp8(y[0], y[1], y[2], y[3]);
    }
  }
  __syncthreads();

  // pem pointer: raw exp gather, layout [t][g][j>>2][c][j&3]; t stride 8192 f4
  const f4* pemP = (const f4*)Pem2 + (8192 + g * 2048 + jw * 4 + kq * 16 + c);

  union BU { v8i v; v4i h[2]; };

  // ones-chain FIRST in each kc group; 5 independent accumulator chains.
  #define LOADMFMA(RDA, RDB)                                                                 \
    BU b0, b1, b2, b3;                                                                       \
    b0.h[0] = *(const v4i*)((RDA) + 0);   b0.h[1] = *(const v4i*)((RDB) + 0);                \
    b1.h[0] = *(const v4i*)((RDA) + 128); b1.h[1] = *(const v4i*)((RDB) + 128);              \
    b2.h[0] = *(const v4i*)((RDA) + 256); b2.h[1] = *(const v4i*)((RDB) + 256);              \
    b3.h[0] = *(const v4i*)((RDA) + 384); b3.h[1] = *(const v4i*)((RDB) + 384);              \
    v4f a0 = {0.f,0.f,0.f,0.f}, a1 = {0.f,0.f,0.f,0.f};                                     \
    v4f a2 = {0.f,0.f,0.f,0.f}, a3 = {0.f,0.f,0.f,0.f};                                     \
    v4f as_ = {0.f,0.f,0.f,0.f};                                                            \
    as_ = __builtin_amdgcn_mfma_scale_f32_16x16x128_f8f6f4(onesv,    b0.v, as_, 0,0,0, 0x7F, 0, 0x7F); \
    a0  = __builtin_amdgcn_mfma_scale_f32_16x16x128_f8f6f4(af[0][0], b0.v, a0, 0,0,0, 0x7F, 0, 0x7F); \
    a1  = __builtin_amdgcn_mfma_scale_f32_16x16x128_f8f6f4(af[1][0], b0.v, a1, 0,0,0, 0x7F, 0, 0x7F); \
    a2  = __builtin_amdgcn_mfma_scale_f32_16x16x128_f8f6f4(af[2][0], b0.v, a2, 0,0,0, 0x7F, 0, 0x7F); \
    a3  = __builtin_amdgcn_mfma_scale_f32_16x16x128_f8f6f4(af[3][0], b0.v, a3, 0,0,0, 0x7F, 0, 0x7F); \
    as_ = __builtin_amdgcn_mfma_scale_f32_16x16x128_f8f6f4(onesv,    b1.v, as_, 0,0,0, 0x7F, 0, 0x7F); \
    a0  = __builtin_amdgcn_mfma_scale_f32_16x16x128_f8f6f4(af[0][1], b1.v, a0, 0,0,0, 0x7F, 0, 0x7F); \
    a1  = __builtin_amdgcn_mfma_scale_f32_16x16x128_f8f6f4(af[1][1], b1.v, a1, 0,0,0, 0x7F, 0, 0x7F); \
    a2  = __builtin_amdgcn_mfma_scale_f32_16x16x128_f8f6f4(af[2][1], b1.v, a2, 0,0,0, 0x7F, 0, 0x7F); \
    a3  = __builtin_amdgcn_mfma_scale_f32_16x16x128_f8f6f4(af[3][1], b1.v, a3, 0,0,0, 0x7F, 0, 0x7F); \
    as_ = __builtin_amdgcn_mfma_scale_f32_16x16x128_f8f6f4(onesv,    b2.v, as_, 0,0,0, 0x7F, 0, 0x7F); \
    a0  = __builtin_amdgcn_mfma_scale_f32_16x16x128_f8f6f4(af[0][2], b2.v, a0, 0,0,0, 0x7F, 0, 0x7F); \
    a1  = __builtin_amdgcn_mfma_scale_f32_16x16x128_f8f6f4(af[1][2], b2.v, a1, 0,0,0, 0x7F, 0, 0x7F); \
    a2  = __builtin_amdgcn_mfma_scale_f32_16x16x128_f8f6f4(af[2][2], b2.v, a2, 0,0,0, 0x7F, 0, 0x7F); \
    a3  = __builtin_amdgcn_mfma_scale_f32_16x16x128_f8f6f4(af[3][2], b2.v, a3, 0,0,0, 0x7F, 0, 0x7F); \
    as_ = __builtin_amdgcn_mfma_scale_f32_16x16x128_f8f6f4(onesv,    b3.v, as_, 0,0,0, 0x7F, 0, 0x7F); \
    a0  = __builtin_amdgcn_mfma_scale_f32_16x16x128_f8f6f4(af[0][3], b3.v, a0, 0,0,0, 0x7F, 0, 0x7F); \
    a1  = __builtin_amdgcn_mfma_scale_f32_16x16x128_f8f6f4(af[1][3], b3.v, a1, 0,0,0, 0x7F, 0, 0x7F); \
    a2  = __builtin_amdgcn_mfma_scale_f32_16x16x128_f8f6f4(af[2][3], b3.v, a2, 0,0,0, 0x7F, 0, 0x7F); \
    a3  = __builtin_amdgcn_mfma_scale_f32_16x16x128_f8f6f4(af[3][3], b3.v, a3, 0,0,0, 0x7F, 0, 0x7F);

  #define EPILOG(WBASE)                                                                      \
    {                                                                                        \
      v4f scl4 = {scl, scl, scl, scl};                                                       \
      v4f v0 = a0 * (pem0 * scl4);                                                           \
      v4f v1 = a1 * (pem1 * scl4);                                                           \
      v4f v2 = a2 * (pem2 * scl4);                                                           \
      v4f v3 = a3 * (pem3 * scl4);                                                           \
      *(int*)((WBASE) + wf0) = pk4fp8(v0[0], v0[1], v0[2], v0[3]);                           \
      *(int*)((WBASE) + wf1) = pk4fp8(v1[0], v1[1], v1[2], v1[3]);                           \
      *(int*)((WBASE) + wf2) = pk4fp8(v2[0], v2[1], v2[2], v2[3]);                           \
      *(int*)((WBASE) + wf3) = pk4fp8(v3[0], v3[1], v3[2], v3[3]);                           \
    }

  for (int t = 1; t <= Tt; t += 2) {
    // ---------- ODD step t (t <= 255 < Tt always): read buf0, write buf1 ----------
    {
      f4 pem0 = pemP[0], pem1 = pemP[64], pem2 = pemP[128], pem3 = pemP[192];
      LOADMFMA(rdA_e, rdB_e)
      float S = as_[0];                     // S_c = sum_k Y_{t-1}[k,c], identical all waves
      int expb = (int)((__float_as_uint(S) >> 23) & 0xFF);
      if (w == 0 && kq == 0 && Tb == t) out[b] = __logf(S) - (float)E * 0.69314718056f;
      E += 150 - expb;                      // E += 23 - ilogb(S)
      float scl = __uint_as_float((unsigned)(254 - expb) << 23);   // 2^-ilogb(S)
      EPILOG(wb_o)
      __syncthreads();
    }
    // ---------- EVEN step t+1: read buf1, write buf0 ----------
    {
      const int T = t + 1;
      if (T < Tt && (T & 31) == 0) ENSURE(T >> 5);
      f4 pem0, pem1, pem2, pem3;
      const f4* p2 = pemP + 8192;          // next timestep (8192 f4 stride)
      if (T < Tt) { pem0 = p2[0]; pem1 = p2[64]; pem2 = p2[128]; pem3 = p2[192]; }
      LOADMFMA(rdA_o, rdB_o)
      float S = as_[0];
      int expb = (int)((__float_as_uint(S) >> 23) & 0xFF);
      if (w == 0 && kq == 0 && Tb == T) out[b] = __logf(S) - (float)E * 0.69314718056f;
      if (T == Tt) goto done;
      E += 150 - expb;
      float scl = __uint_as_float((unsigned)(254 - expb) << 23);
      EPILOG(wb_e)
      __syncthreads();
    }
    pemP += 16384;                          // two timesteps
  }
done: ;
  #undef LOADMFMA
  #undef EPILOG
  #undef ENSURE
}

extern "C" void kernel_launch(void* const* d_in, const int* in_sizes, int n_in,
                              void* d_out, int out_size, void* d_ws, size_t ws_size,
                              hipStream_t stream) {
  const int*   x     = (const int*)  d_in[0];
  const int*   Tlen  = (const int*)  d_in[1];
  const float* trans = (const float*)d_in[2];
  const float* emis  = (const float*)d_in[3];
  const float* prior = (const float*)d_in[4];
  float* out = (float*)d_out;

  char* w = (char*)d_ws;
  float* colsum   = (float*)(w + (512 << 10));         // 2 KB (atomic-accumulated)
  float* rowsum   = (float*)(w + (512 << 10) + 2048);  // 2 KB
  int*   progress = (int*)  (w + (512 << 10) + 4096);  // 10 counters
  float* Pem2     = (float*)(w + (1024 << 10));        // 32 MB Pem2raw[t][g][j>>2][c][j&3]

  hipMemsetAsync(w + (512 << 10), 0, 8192, stream);    // colsum + rowsum + progress
  k_all<<<NCONS + NPROD + NPRE, 512, 0, stream>>>(trans, emis, x, prior, Tlen,
                                                  colsum, rowsum, Pem2, progress, out);
}

// Round 23
// 290.814 us; speedup vs baseline: 1.3296x; 1.3296x over previous
//
#include <hip/hip_runtime.h>
#include <math.h>

#define Nn 512
#define Mm 32000
#define Bb 64
#define Tt 256
#define NCONS 4     // consumer (recursion) blocks, 512 threads / 8 waves each
#define NPROD 128   // producer (emission) blocks

typedef float v4f __attribute__((ext_vector_type(4)));
typedef float f4  __attribute__((ext_vector_type(4)));
typedef int   v4i __attribute__((ext_vector_type(4)));
typedef int   v8i __attribute__((ext_vector_type(8)));

// pack 4 f32 -> 4 OCP e4m3 bytes in an int
__device__ inline int pk4fp8(float a, float b, float c, float d) {
  int r = __builtin_amdgcn_cvt_pk_fp8_f32(a, b, 0, false);
  r = __builtin_amdgcn_cvt_pk_fp8_f32(c, d, r, true);
  return r;
}

// ---- colsum[k] = sum_j exp(trans[j][k]) ----
__global__ void k_colsum(const float* __restrict__ trans, float* __restrict__ colsum) {
  int tid = threadIdx.x;
  int j0 = blockIdx.x * 16;
  float a0 = 0.f, a1 = 0.f;
  for (int r = 0; r < 16; ++r) {
    a0 += __expf(trans[(j0 + r) * Nn + tid]);
    a1 += __expf(trans[(j0 + r) * Nn + 256 + tid]);
  }
  atomicAdd(&colsum[tid], a0);
  atomicAdd(&colsum[256 + tid], a1);
}

// ---- A_s[j][k] = 256*exp(trans[j][k])/colsum[k] as e4m3 ----
__global__ void k_writeA8(const float* __restrict__ trans, const float* __restrict__ colsum,
                          int* __restrict__ A8) {
  int d = blockIdx.x * 256 + threadIdx.x;
  int j = d >> 7, k0 = (d & 127) << 2;
  float v0 = 256.f * __expf(trans[j * Nn + k0 + 0]) / colsum[k0 + 0];
  float v1 = 256.f * __expf(trans[j * Nn + k0 + 1]) / colsum[k0 + 1];
  float v2 = 256.f * __expf(trans[j * Nn + k0 + 2]) / colsum[k0 + 2];
  float v3 = 256.f * __expf(trans[j * Nn + k0 + 3]) / colsum[k0 + 3];
  A8[d] = pk4fp8(v0, v1, v2, v3);
}

// ---- fused: blocks 0-3 recursion consumers (8 waves, 64 A-rows/wave), 4-131 producers ----
// r20 restored (best verified: 291.6us, absmax 16.0). Ones-MFMA S (5th independent
// chain, ones-first ordering), same-step scl, x2-unrolled static-parity loop.
__global__ __attribute__((amdgpu_flat_work_group_size(512, 512), amdgpu_waves_per_eu(2, 2)))
void k_fused(
    const char* __restrict__ A8, const float* __restrict__ emis,
    const int* __restrict__ x, const float* __restrict__ prior,
    const int* __restrict__ Tlen, float* __restrict__ Pem2,
    int* __restrict__ progress, float* __restrict__ out)
{
  __shared__ __align__(16) char ybuf[2][16 * Nn];   // fp8 Y [c][k], XOR-swizzled; 16 KB
  __shared__ __align__(16) float ss[512];
  __shared__ __align__(16) f4 ss4[512];
  const int tid = threadIdx.x;

  if (blockIdx.x >= NCONS) {
    // ================= producer: 4 emis rows, Pem2 in 32-t chunks =================
    const int p = blockIdx.x - NCONS;      // j-quad p -> emis rows 4p..4p+3
    const int j0 = p * 4;

    // ptot = sum exp(prior)  (512 threads == Nn)
    float e = __expf(prior[tid]);
    ss[tid] = e; __syncthreads();
    for (int off = 256; off; off >>= 1) { if (tid < off) ss[tid] += ss[tid + off]; __syncthreads(); }
    const float ptot = ss[0];

    // single-pass interleaved row-sums for the 4 rows
    const f4* q0 = (const f4*)(emis + (size_t)(j0 + 0) * Mm);
    const f4* q1 = (const f4*)(emis + (size_t)(j0 + 1) * Mm);
    const f4* q2 = (const f4*)(emis + (size_t)(j0 + 2) * Mm);
    const f4* q3 = (const f4*)(emis + (size_t)(j0 + 3) * Mm);
    f4 a4 = {0.f, 0.f, 0.f, 0.f};
    for (int i = tid; i < Mm / 4; i += 512) {
      f4 v0 = q0[i], v1 = q1[i], v2 = q2[i], v3 = q3[i];
      a4[0] += (__expf(v0[0]) + __expf(v0[1])) + (__expf(v0[2]) + __expf(v0[3]));
      a4[1] += (__expf(v1[0]) + __expf(v1[1])) + (__expf(v1[2]) + __expf(v1[3]));
      a4[2] += (__expf(v2[0]) + __expf(v2[1])) + (__expf(v2[2]) + __expf(v2[3]));
      a4[3] += (__expf(v3[0]) + __expf(v3[1])) + (__expf(v3[2]) + __expf(v3[3]));
    }
    ss4[tid] = a4; __syncthreads();
    for (int off = 256; off; off >>= 1) { if (tid < off) ss4[tid] += ss4[tid + off]; __syncthreads(); }
    f4 tot = ss4[0];
    f4 rs, fz;
    #pragma unroll
    for (int q = 0; q < 4; ++q) {
      rs[q] = 32768.f / tot[q];                               // 2^15 scale
      fz[q] = rs[q] * 256.f * __expf(prior[j0 + q]) / ptot;   // t=0: * 2^8 * pi
    }

    // gather + publish in 32-timestep chunks
    const float* r0 = emis + (size_t)(j0 + 0) * Mm;
    const float* r1 = emis + (size_t)(j0 + 1) * Mm;
    const float* r2 = emis + (size_t)(j0 + 2) * Mm;
    const float* r3 = emis + (size_t)(j0 + 3) * Mm;
    f4* P4 = (f4*)Pem2;
    for (int c8 = 0; c8 < 8; ++c8) {
      #pragma unroll
      for (int r = 0; r < 4; ++r) {
        int idx = c8 * 2048 + r * 512 + tid;
        int t = idx >> 6, b = idx & 63;
        int mv = x[b * Tt + t];
        f4 fq = (t == 0) ? fz : rs;
        f4 o = { __expf(r0[mv]) * fq[0], __expf(r1[mv]) * fq[1],
                 __expf(r2[mv]) * fq[2], __expf(r3[mv]) * fq[3] };
        P4[t * 8192 + (b >> 4) * 2048 + p * 16 + (b & 15)] = o;
      }
      __syncthreads();
      if (tid == 0) {
        __builtin_amdgcn_fence(__ATOMIC_RELEASE, "agent");
        __hip_atomic_fetch_add(&progress[c8], 1, __ATOMIC_RELAXED, __HIP_MEMORY_SCOPE_AGENT);
      }
    }
    return;
  }

  // ================= consumer: 8 waves, 64 A-rows each =================
  const int g = blockIdx.x;
  const int w = tid >> 6, lane = tid & 63;
  const int c = lane & 15, kq = lane >> 4;
  const int jw = w * 64;                    // this wave's 64 A-rows
  const int swz = (c & 7) << 4;
  const int b = g * 16 + c;

  // A fragments (one-time): lane holds A_s[jw+rt*16+c][kc*128+kq*32 .. +31]  (128 regs)
  v8i af[4][4];
  #pragma unroll
  for (int rt = 0; rt < 4; ++rt)
    #pragma unroll
    for (int kc = 0; kc < 4; ++kc)
      af[rt][kc] = *reinterpret_cast<const v8i*>(
          A8 + (size_t)(jw + rt * 16 + c) * Nn + kc * 128 + kq * 32);

  // ones-A operand: e4m3 1.0 = 0x38 in all 32 bytes
  v8i onesv;
  #pragma unroll
  for (int u = 0; u < 8; ++u) onesv[u] = 0x38383838;

  // launder: block rematerialization/sinking into the loop
  #pragma unroll
  for (int rt = 0; rt < 4; ++rt)
    #pragma unroll
    for (int kc = 0; kc < 4; ++kc)
      asm volatile("" : "+v"(af[rt][kc]));
  asm volatile("" : "+v"(onesv));

  const int Tb = Tlen[b];
  int E = 23;                               // Y = 2^E * alpha
  int csafe = 0;

  #define ENSURE(NEED)                                                                      \
    while (csafe <= (NEED)) {                                                               \
      if (__hip_atomic_load(&progress[csafe], __ATOMIC_RELAXED,                             \
                            __HIP_MEMORY_SCOPE_AGENT) >= NPROD) {                           \
        ++csafe;                                                                            \
        __builtin_amdgcn_fence(__ATOMIC_ACQUIRE, "agent");                                  \
      } else __builtin_amdgcn_s_sleep(2);                                                   \
    }

  // LDS byte offsets. Writes use XOR (wf_rt = wf0 ^ rt*16); reads add kc*128.
  const int roA0 = (c * Nn + kq * 32) ^ swz;
  const int roB0 = roA0 ^ 16;
  const int wf0 = (c * Nn + jw + kq * 4) ^ swz;
  const int wf1 = wf0 ^ 16, wf2 = wf0 ^ 32, wf3 = wf0 ^ 48;
  char* const yb0 = &ybuf[0][0];

  // precomputed loop-invariant bases (odd step: read buf0 -> write buf1)
  const char* rdA_e = yb0 + roA0;          // odd-step read bases (buf0)
  const char* rdB_e = yb0 + roB0;
  const char* rdA_o = rdA_e + 8192;        // even-step read bases (buf1)
  const char* rdB_o = rdB_e + 8192;
  char* const wb_o = yb0 + 8192;           // odd-step write base (buf1)
  char* const wb_e = yb0;                  // even-step write base (buf0)

  ENSURE(0);                                // Pem2 chunk 0 ready

  // init: Y0 = Pem2[0] (includes 2^23 * pi * emprob); 512 threads, 16 rows each
  {
    int cc = tid & 15, grp = tid >> 4, jb = grp * 16, sz = (cc & 7) << 4;
    const f4* P0 = (const f4*)Pem2 + g * 2048 + (jb >> 2) * 16 + cc;
    #pragma unroll
    for (int q = 0; q < 4; ++q) {
      f4 v = P0[q * 16];
      *reinterpret_cast<int*>(yb0 + ((cc * Nn + jb + q * 4) ^ sz)) = pk4fp8(v[0], v[1], v[2], v[3]);
    }
  }
  __syncthreads();

  // pem pointer: PIDX(1,0) = 8192 + g*2048 + jw*4 + kq*16 + c (f4 units);
  // RT stride 64 f4 (imm offsets); timestep stride 8192 f4.
  const f4* pemP = (const f4*)Pem2 + (8192 + g * 2048 + jw * 4 + kq * 16 + c);

  union BU { v8i v; v4i h[2]; };

  // ones-chain FIRST in each kc group: as_ completes 4 MFMA slots before the step
  // end, so the serial S->expb->scl->pem*scl chain overlaps the last a_rt MFMAs.
  // 5 independent accumulator chains, dep distance 5.
  #define LOADMFMA(RDA, RDB)                                                                 \
    BU b0, b1, b2, b3;                                                                       \
    b0.h[0] = *(const v4i*)((RDA) + 0);   b0.h[1] = *(const v4i*)((RDB) + 0);                \
    b1.h[0] = *(const v4i*)((RDA) + 128); b1.h[1] = *(const v4i*)((RDB) + 128);              \
    b2.h[0] = *(const v4i*)((RDA) + 256); b2.h[1] = *(const v4i*)((RDB) + 256);              \
    b3.h[0] = *(const v4i*)((RDA) + 384); b3.h[1] = *(const v4i*)((RDB) + 384);              \
    v4f a0 = {0.f,0.f,0.f,0.f}, a1 = {0.f,0.f,0.f,0.f};                                     \
    v4f a2 = {0.f,0.f,0.f,0.f}, a3 = {0.f,0.f,0.f,0.f};                                     \
    v4f as_ = {0.f,0.f,0.f,0.f};                                                            \
    as_ = __builtin_amdgcn_mfma_scale_f32_16x16x128_f8f6f4(onesv,    b0.v, as_, 0,0,0, 0x7F, 0, 0x7F); \
    a0  = __builtin_amdgcn_mfma_scale_f32_16x16x128_f8f6f4(af[0][0], b0.v, a0, 0,0,0, 0x7F, 0, 0x7F); \
    a1  = __builtin_amdgcn_mfma_scale_f32_16x16x128_f8f6f4(af[1][0], b0.v, a1, 0,0,0, 0x7F, 0, 0x7F); \
    a2  = __builtin_amdgcn_mfma_scale_f32_16x16x128_f8f6f4(af[2][0], b0.v, a2, 0,0,0, 0x7F, 0, 0x7F); \
    a3  = __builtin_amdgcn_mfma_scale_f32_16x16x128_f8f6f4(af[3][0], b0.v, a3, 0,0,0, 0x7F, 0, 0x7F); \
    as_ = __builtin_amdgcn_mfma_scale_f32_16x16x128_f8f6f4(onesv,    b1.v, as_, 0,0,0, 0x7F, 0, 0x7F); \
    a0  = __builtin_amdgcn_mfma_scale_f32_16x16x128_f8f6f4(af[0][1], b1.v, a0, 0,0,0, 0x7F, 0, 0x7F); \
    a1  = __builtin_amdgcn_mfma_scale_f32_16x16x128_f8f6f4(af[1][1], b1.v, a1, 0,0,0, 0x7F, 0, 0x7F); \
    a2  = __builtin_amdgcn_mfma_scale_f32_16x16x128_f8f6f4(af[2][1], b1.v, a2, 0,0,0, 0x7F, 0, 0x7F); \
    a3  = __builtin_amdgcn_mfma_scale_f32_16x16x128_f8f6f4(af[3][1], b1.v, a3, 0,0,0, 0x7F, 0, 0x7F); \
    as_ = __builtin_amdgcn_mfma_scale_f32_16x16x128_f8f6f4(onesv,    b2.v, as_, 0,0,0, 0x7F, 0, 0x7F); \
    a0  = __builtin_amdgcn_mfma_scale_f32_16x16x128_f8f6f4(af[0][2], b2.v, a0, 0,0,0, 0x7F, 0, 0x7F); \
    a1  = __builtin_amdgcn_mfma_scale_f32_16x16x128_f8f6f4(af[1][2], b2.v, a1, 0,0,0, 0x7F, 0, 0x7F); \
    a2  = __builtin_amdgcn_mfma_scale_f32_16x16x128_f8f6f4(af[2][2], b2.v, a2, 0,0,0, 0x7F, 0, 0x7F); \
    a3  = __builtin_amdgcn_mfma_scale_f32_16x16x128_f8f6f4(af[3][2], b2.v, a3, 0,0,0, 0x7F, 0, 0x7F); \
    as_ = __builtin_amdgcn_mfma_scale_f32_16x16x128_f8f6f4(onesv,    b3.v, as_, 0,0,0, 0x7F, 0, 0x7F); \
    a0  = __builtin_amdgcn_mfma_scale_f32_16x16x128_f8f6f4(af[0][3], b3.v, a0, 0,0,0, 0x7F, 0, 0x7F); \
    a1  = __builtin_amdgcn_mfma_scale_f32_16x16x128_f8f6f4(af[1][3], b3.v, a1, 0,0,0, 0x7F, 0, 0x7F); \
    a2  = __builtin_amdgcn_mfma_scale_f32_16x16x128_f8f6f4(af[2][3], b3.v, a2, 0,0,0, 0x7F, 0, 0x7F); \
    a3  = __builtin_amdgcn_mfma_scale_f32_16x16x128_f8f6f4(af[3][3], b3.v, a3, 0,0,0, 0x7F, 0, 0x7F);

  #define EPILOG(WBASE)                                                                      \
    {                                                                                        \
      v4f scl4 = {scl, scl, scl, scl};                                                       \
      v4f v0 = a0 * (pem0 * scl4);                                                           \
      v4f v1 = a1 * (pem1 * scl4);                                                           \
      v4f v2 = a2 * (pem2 * scl4);                                                           \
      v4f v3 = a3 * (pem3 * scl4);                                                           \
      *(int*)((WBASE) + wf0) = pk4fp8(v0[0], v0[1], v0[2], v0[3]);                           \
      *(int*)((WBASE) + wf1) = pk4fp8(v1[0], v1[1], v1[2], v1[3]);                           \
      *(int*)((WBASE) + wf2) = pk4fp8(v2[0], v2[1], v2[2], v2[3]);                           \
      *(int*)((WBASE) + wf3) = pk4fp8(v3[0], v3[1], v3[2], v3[3]);                           \
    }

  for (int t = 1; t <= Tt; t += 2) {
    // ---------- ODD step t (t <= 255 < Tt always): read buf0, write buf1 ----------
    {
      f4 pem0 = pemP[0], pem1 = pemP[64], pem2 = pemP[128], pem3 = pemP[192];
      LOADMFMA(rdA_e, rdB_e)
      float S = as_[0];                     // S_c = sum_k Y_{t-1}[k,c], identical all waves
      int expb = (int)((__float_as_uint(S) >> 23) & 0xFF);
      if (w == 0 && kq == 0 && Tb == t) out[b] = __logf(S) - (float)E * 0.69314718056f;
      E += 150 - expb;                      // E += 23 - ilogb(S)
      float scl = __uint_as_float((unsigned)(254 - expb) << 23);   // 2^-ilogb(S)
      EPILOG(wb_o)
      __syncthreads();
    }
    // ---------- EVEN step t+1: read buf1, write buf0 ----------
    {
      const int T = t + 1;
      if (T < Tt && (T & 31) == 0) ENSURE(T >> 5);
      f4 pem0, pem1, pem2, pem3;
      const f4* p2 = pemP + 8192;          // next timestep (8192 f4 stride)
      if (T < Tt) { pem0 = p2[0]; pem1 = p2[64]; pem2 = p2[128]; pem3 = p2[192]; }
      LOADMFMA(rdA_o, rdB_o)
      float S = as_[0];
      int expb = (int)((__float_as_uint(S) >> 23) & 0xFF);
      if (w == 0 && kq == 0 && Tb == T) out[b] = __logf(S) - (float)E * 0.69314718056f;
      if (T == Tt) goto done;
      E += 150 - expb;
      float scl = __uint_as_float((unsigned)(254 - expb) << 23);
      EPILOG(wb_e)
      __syncthreads();
    }
    pemP += 16384;                          // two timesteps
  }
done: ;
  #undef LOADMFMA
  #undef EPILOG
  #undef ENSURE
}

extern "C" void kernel_launch(void* const* d_in, const int* in_sizes, int n_in,
                              void* d_out, int out_size, void* d_ws, size_t ws_size,
                              hipStream_t stream) {
  const int*   x     = (const int*)  d_in[0];
  const int*   Tlen  = (const int*)  d_in[1];
  const float* trans = (const float*)d_in[2];
  const float* emis  = (const float*)d_in[3];
  const float* prior = (const float*)d_in[4];
  float* out = (float*)d_out;

  char* w = (char*)d_ws;
  char*  A8       = (char*)(w);                        // 256 KB fp8 A_s[j][k]
  float* colsum   = (float*)(w + (512 << 10));         // 2 KB
  int*   progress = (int*)  (w + (512 << 10) + 4096);  // 8 chunk counters
  float* Pem2     = (float*)(w + (1024 << 10));        // 32 MB Pem2[t][g][j>>2][c][j&3]

  hipMemsetAsync(w + (512 << 10), 0, 8192, stream);    // colsum + progress
  k_colsum <<<32,  256, 0, stream>>>(trans, colsum);
  k_writeA8<<<256, 256, 0, stream>>>(trans, colsum, (int*)A8);
  k_fused  <<<NCONS + NPROD, 512, 0, stream>>>(A8, emis, x, prior, Tlen, Pem2, progress, out);
}